// Round 2
// 194.206 us; speedup vs baseline: 1.0216x; 1.0216x over previous
//
#include <hip/hip_runtime.h>
#include <stdint.h>

#define BATCH 8
#define K_DIM 4096
#define N_DIM 16384
#define KH (K_DIM / 2)          // 2048 packed bytes per output row (one per int32)
#define NPAIR (K_DIM / 2)       // 2048 column pairs
#define BLOCK 512               // 8 waves
#define ROWS_PER_WAVE 4
#define ROWS_PER_BLOCK 32       // 8 waves * 4 rows
#define ITERS (KH / 4 / 64)     // 8 iterations of dwordx4 per lane

typedef _Float16 h2 __attribute__((ext_vector_type(2)));
typedef int i4 __attribute__((ext_vector_type(4)));

__device__ __forceinline__ h2 as_h2(uint32_t u) { return __builtin_bit_cast(h2, u); }

// v_dot2_f32_f16: 2 f16 MACs, f32 accumulate
__device__ __forceinline__ float fdot2f(h2 a, h2 b, float c) {
#if __has_builtin(__builtin_amdgcn_fdot2)
    return __builtin_amdgcn_fdot2(a, b, c, false);
#else
    return fmaf((float)a[1], (float)b[1], fmaf((float)a[0], (float)b[0], c));
#endif
}

// LDS layout: column pair p (cols 2p, 2p+1) occupies chunks 2p (batches 0-3)
// and 2p+1 (batches 4-7); each chunk = 4x u32, each u32 = f16x2
// (x[2p][b] low, x[2p+1][b] high). phys = c ^ ((c>>3)&7): within any 8
// consecutive logical chunks the physical chunks hit all 8 quad-bank groups
// -> b128 reads/writes conflict-free in 8-lane groups (2 lanes/bank = free).
__global__ __launch_bounds__(BLOCK, 4)   // 4 waves/EU => 2 blocks/CU, VGPR<=128
void w4a16_gemv(const float* __restrict__ x,       // [8][4096] f32 (fp16 upcast)
                const int*   __restrict__ w,       // [16384][2048] int32 (byte each)
                const float* __restrict__ scales,  // [16384] f32
                float*       __restrict__ out)     // [8][16384] f32
{
    __shared__ uint4 xchunks[2 * NPAIR];   // 64 KiB
    const int tid = threadIdx.x;

    // ---- stage x -> LDS as f16 column-pairs (exact: x originated as fp16) ----
    #pragma unroll
    for (int it = 0; it < NPAIR / BLOCK; ++it) {   // 4 iterations
        const int p = it * BLOCK + tid;
        uint32_t pk[BATCH];
        #pragma unroll
        for (int b = 0; b < BATCH; ++b) {
            const float2 v = *reinterpret_cast<const float2*>(x + (size_t)b * K_DIM + 2 * p);
            pk[b] = __builtin_bit_cast(uint32_t, __builtin_amdgcn_cvt_pkrtz(v.x, v.y)); // RTZ exact here
        }
        const int c0 = 2 * p, c1 = 2 * p + 1;
        xchunks[c0 ^ ((c0 >> 3) & 7)] = make_uint4(pk[0], pk[1], pk[2], pk[3]);
        xchunks[c1 ^ ((c1 >> 3) & 7)] = make_uint4(pk[4], pk[5], pk[6], pk[7]);
    }
    __syncthreads();

    const int wave = tid >> 6;
    const int lane = tid & 63;
    const int row0 = blockIdx.x * ROWS_PER_BLOCK + wave * ROWS_PER_WAVE;

    const i4* __restrict__ wv0 = (const i4*)(w + (size_t)(row0 + 0) * KH);
    const i4* __restrict__ wv1 = (const i4*)(w + (size_t)(row0 + 1) * KH);
    const i4* __restrict__ wv2 = (const i4*)(w + (size_t)(row0 + 2) * KH);
    const i4* __restrict__ wv3 = (const i4*)(w + (size_t)(row0 + 3) * KH);

    float acc[ROWS_PER_WAVE][BATCH];
    #pragma unroll
    for (int j = 0; j < ROWS_PER_WAVE; ++j)
        #pragma unroll
        for (int b = 0; b < BATCH; ++b) acc[j][b] = 0.0f;

    const h2 neg1032 = as_h2(0xE408E408u);   // (-1032, -1032) f16

    // first tile
    int qw[4][4];
    {
        const i4 a = __builtin_nontemporal_load(wv0 + lane);
        const i4 b = __builtin_nontemporal_load(wv1 + lane);
        const i4 c = __builtin_nontemporal_load(wv2 + lane);
        const i4 d = __builtin_nontemporal_load(wv3 + lane);
        qw[0][0] = a[0]; qw[0][1] = a[1]; qw[0][2] = a[2]; qw[0][3] = a[3];
        qw[1][0] = b[0]; qw[1][1] = b[1]; qw[1][2] = b[2]; qw[1][3] = b[3];
        qw[2][0] = c[0]; qw[2][1] = c[1]; qw[2][2] = c[2]; qw[2][3] = c[3];
        qw[3][0] = d[0]; qw[3][1] = d[1]; qw[3][2] = d[2]; qw[3][3] = d[3];
    }

    auto compute = [&](int t) {
        const int u = (t << 6) + lane;       // dwordx4 index within row
        const int cbase = u << 3;            // chunk base (pair 4u -> chunk 8u)
        const int xork = u & 7;
        #pragma unroll
        for (int m = 0; m < 4; ++m) {
            // byte m of this dwordx4 = column pair p = 4u+m
            const uint4 xa = xchunks[cbase + ((2 * m)     ^ xork)];   // batches 0-3
            const uint4 xb = xchunks[cbase + ((2 * m + 1) ^ xork)];   // batches 4-7
            #pragma unroll
            for (int j = 0; j < ROWS_PER_WAVE; ++j) {
                // magic dequant: place nibbles in f16 mantissas (1024+n), flip
                // sign bit of each nibble (n^8), then subtract 1032 packed:
                // result = exact signed int4 pair as f16x2. 5 VALU ops total.
                const uint32_t bv = (uint32_t)qw[j][m];
                const uint32_t tt = (bv & 0xFu) | ((bv << 12) & 0x000F0000u);
                const h2 w2 = as_h2(tt ^ 0x64086408u) + neg1032;
                acc[j][0] = fdot2f(w2, as_h2(xa.x), acc[j][0]);
                acc[j][1] = fdot2f(w2, as_h2(xa.y), acc[j][1]);
                acc[j][2] = fdot2f(w2, as_h2(xa.z), acc[j][2]);
                acc[j][3] = fdot2f(w2, as_h2(xa.w), acc[j][3]);
                acc[j][4] = fdot2f(w2, as_h2(xb.x), acc[j][4]);
                acc[j][5] = fdot2f(w2, as_h2(xb.y), acc[j][5]);
                acc[j][6] = fdot2f(w2, as_h2(xb.z), acc[j][6]);
                acc[j][7] = fdot2f(w2, as_h2(xb.w), acc[j][7]);
            }
        }
    };

    // software pipeline: next tile's 4 loads stay in flight across compute
    #pragma unroll 1
    for (int t = 0; t < ITERS - 1; ++t) {
        const int un = ((t + 1) << 6) + lane;
        const i4 a = __builtin_nontemporal_load(wv0 + un);
        const i4 b = __builtin_nontemporal_load(wv1 + un);
        const i4 c = __builtin_nontemporal_load(wv2 + un);
        const i4 d = __builtin_nontemporal_load(wv3 + un);
        compute(t);
        qw[0][0] = a[0]; qw[0][1] = a[1]; qw[0][2] = a[2]; qw[0][3] = a[3];
        qw[1][0] = b[0]; qw[1][1] = b[1]; qw[1][2] = b[2]; qw[1][3] = b[3];
        qw[2][0] = c[0]; qw[2][1] = c[1]; qw[2][2] = c[2]; qw[2][3] = c[3];
        qw[3][0] = d[0]; qw[3][1] = d[1]; qw[3][2] = d[2]; qw[3][3] = d[3];
    }
    compute(ITERS - 1);

    // ---- 32-value tree reduction; value j*8+b lands on lane j*8+b ----
    float vals[32];
    #pragma unroll
    for (int j = 0; j < ROWS_PER_WAVE; ++j)
        #pragma unroll
        for (int b = 0; b < BATCH; ++b) vals[j * 8 + b] = acc[j][b];

    #pragma unroll
    for (int k = 0; k < 5; ++k) {
        const int sel = (lane >> k) & 1;
        const int n = 32 >> k;
        #pragma unroll
        for (int i = 0; i < n / 2; ++i) {
            const float a = vals[2 * i];
            const float c = vals[2 * i + 1];
            const float mine  = sel ? c : a;
            const float other = sel ? a : c;
            vals[i] = mine + __shfl_xor(other, 1 << k, 64);
        }
    }
    const float total = vals[0] + __shfl_xor(vals[0], 32, 64);

    if (lane < 32) {
        const int r = row0 + (lane >> 3);      // j = lane>>3, b = lane&7
        out[(size_t)(lane & 7) * N_DIM + r] = total * scales[r];
    }
}

extern "C" void kernel_launch(void* const* d_in, const int* in_sizes, int n_in,
                              void* d_out, int out_size, void* d_ws, size_t ws_size,
                              hipStream_t stream) {
    const float* x      = (const float*)d_in[0];
    const int*   w      = (const int*)d_in[1];
    const float* scales = (const float*)d_in[2];
    float*       out    = (float*)d_out;

    dim3 grid(N_DIM / ROWS_PER_BLOCK);   // 512
    dim3 block(BLOCK);                   // 512
    hipLaunchKernelGGL(w4a16_gemv, grid, block, 0, stream, x, w, scales, out);
}